// Round 1
// baseline (1080.066 us; speedup 1.0000x reference)
//
#include <hip/hip_runtime.h>
#include <hip/hip_bf16.h>

// ---------------- constants ----------------
constexpr int B_ = 8, C_ = 128, Hh = 64, Ww = 64, L_ = Hh * Ww;   // L = 4096
constexpr int CIN_ = 192, K_ = 4, Rr = 8, DFF_ = 512;
constexpr long SZ1 = (long)B_ * C_ * L_;                           // 4,194,304 floats
constexpr int CH_ = 64, NCH_ = L_ / CH_;                           // 64 chunks of 64
constexpr float EPSf = 1e-5f;

#define DEVI __device__ __forceinline__

DEVI float sigm(float x) { return 1.f / (1.f + expf(-x)); }
DEVI float softplusf(float x) { return x > 20.f ? x : log1pf(expf(x)); }
DEVI float geluf(float x) { return 0.5f * x * (1.f + erff(x * 0.70710678118654752f)); }
DEVI float siluf(float x) { return x * sigm(x); }

// ---------------- generic tiled fp32 GEMM ----------------
// C[M,N] (+)= W[M,K] @ X[K,N]  (+ bias[m]) (sigmoid) ; X may be split (concat) or gelu'd on load.
// grid: (N/64, M/128, batches). Row stride of X and C is N. Per-batch strides sX1/sX2/sC.
template <bool ACC, bool BIAS, bool XGELU, bool SIG, bool SPLIT>
__global__ __launch_bounds__(256) void gemm_k(
    const float* __restrict__ W, const float* __restrict__ X1, long sX1,
    const float* __restrict__ X2, long sX2, int splitRow,
    const float* __restrict__ bias, float* __restrict__ Cp, long sC,
    int M, int N, int K)
{
    __shared__ float sW[32][128];
    __shared__ float sX[32][64];
    const int tid = threadIdx.x;
    const int bn = blockIdx.x, bm = blockIdx.y, bz = blockIdx.z;
    const float* X1b = X1 + (long)bz * sX1;
    const float* X2b = SPLIT ? (X2 + (long)bz * sX2) : nullptr;
    float* Cb = Cp + (long)bz * sC;
    const int n0 = bn * 64, m0 = bm * 128;
    const int tx = tid & 15, ty = tid >> 4;

    float acc[8][4];
#pragma unroll
    for (int i = 0; i < 8; i++)
#pragma unroll
        for (int j = 0; j < 4; j++) acc[i][j] = 0.f;

    const int wrow = tid >> 1;           // 0..127
    const int wk0  = (tid & 1) * 16;     // 0 / 16
    const int xrow = tid >> 3;           // 0..31
    const int xcol = (tid & 7) * 8;      // 0..56

    for (int k0 = 0; k0 < K; k0 += 32) {
        // stage W tile (transposed into LDS)
        {
            const float* wp = W + (long)(m0 + wrow) * K + k0 + wk0;
#pragma unroll
            for (int j = 0; j < 4; j++) {
                float4 v = *(const float4*)(wp + j * 4);
                int kk = wk0 + j * 4;
                sW[kk + 0][wrow] = v.x; sW[kk + 1][wrow] = v.y;
                sW[kk + 2][wrow] = v.z; sW[kk + 3][wrow] = v.w;
            }
        }
        // stage X tile
        {
            const int krow = k0 + xrow;
            const float* xp;
            if (SPLIT && krow >= splitRow)
                xp = X2b + (long)(krow - splitRow) * N + n0 + xcol;
            else
                xp = X1b + (long)krow * N + n0 + xcol;
            float4 a = *(const float4*)xp;
            float4 b = *(const float4*)(xp + 4);
            if (XGELU) {
                a.x = geluf(a.x); a.y = geluf(a.y); a.z = geluf(a.z); a.w = geluf(a.w);
                b.x = geluf(b.x); b.y = geluf(b.y); b.z = geluf(b.z); b.w = geluf(b.w);
            }
            *(float4*)&sX[xrow][xcol] = a;
            *(float4*)&sX[xrow][xcol + 4] = b;
        }
        __syncthreads();
#pragma unroll
        for (int kk = 0; kk < 32; kk++) {
            float4 xv = *(const float4*)&sX[kk][tx << 2];
            float4 wa = *(const float4*)&sW[kk][ty << 3];
            float4 wb = *(const float4*)&sW[kk][(ty << 3) + 4];
            float wv[8] = {wa.x, wa.y, wa.z, wa.w, wb.x, wb.y, wb.z, wb.w};
            float xu[4] = {xv.x, xv.y, xv.z, xv.w};
#pragma unroll
            for (int i = 0; i < 8; i++)
#pragma unroll
                for (int j = 0; j < 4; j++) acc[i][j] += wv[i] * xu[j];
        }
        __syncthreads();
    }

#pragma unroll
    for (int i = 0; i < 8; i++) {
        int m = m0 + (ty << 3) + i;
        float bv = BIAS ? bias[m] : 0.f;
        float* cp = Cb + (long)m * N + n0 + (tx << 2);
        float4 o = make_float4(acc[i][0] + bv, acc[i][1] + bv, acc[i][2] + bv, acc[i][3] + bv);
        if (ACC) {
            float4 p = *(const float4*)cp;
            o.x += p.x; o.y += p.y; o.z += p.z; o.w += p.w;
        }
        if (SIG) { o.x = sigm(o.x); o.y = sigm(o.y); o.z = sigm(o.z); o.w = sigm(o.w); }
        *(float4*)cp = o;
    }
}

// ---------------- channel LayerNorm (channel_first) ----------------
// block = 256 = 64 positions x 4 channel-quarters; grid = B*L/64
__global__ __launch_bounds__(256) void ln_cf_k(const float* __restrict__ in,
                                               const float* __restrict__ g,
                                               const float* __restrict__ bta,
                                               float* __restrict__ out)
{
    __shared__ float s1[4][64], s2[4][64];
    const int tid = threadIdx.x;
    const int p = tid & 63, q = tid >> 6;
    const long posg = (long)blockIdx.x * 64 + p;
    const int b = (int)(posg / L_);
    const int pp = (int)(posg % L_);
    const float* base = in + ((long)b * C_ + q * 32) * L_ + pp;
    float v[32];
    float s = 0.f, sq = 0.f;
#pragma unroll
    for (int i = 0; i < 32; i++) {
        float t = base[(long)i * L_];
        v[i] = t; s += t; sq += t * t;
    }
    s1[q][p] = s; s2[q][p] = sq;
    __syncthreads();
    float ts = s1[0][p] + s1[1][p] + s1[2][p] + s1[3][p];
    float tq = s2[0][p] + s2[1][p] + s2[2][p] + s2[3][p];
    float mu = ts * (1.f / 128.f);
    float var = tq * (1.f / 128.f) - mu * mu;
    float rs = rsqrtf(var + EPSf);
    float* ob = out + ((long)b * C_ + q * 32) * L_ + pp;
#pragma unroll
    for (int i = 0; i < 32; i++) {
        int c = q * 32 + i;
        ob[(long)i * L_] = (v[i] - mu) * rs * g[c] + bta[c];
    }
}

// ---------------- depthwise 3x3 conv + bias + SiLU ----------------
__global__ __launch_bounds__(256) void dwconv_silu_k(const float* __restrict__ in,
                                                     const float* __restrict__ wts,
                                                     const float* __restrict__ bias,
                                                     float* __restrict__ out)
{
    const long idx = (long)blockIdx.x * 256 + threadIdx.x;  // < B*C*H*W
    const int w = (int)(idx & 63);
    const int h = (int)((idx >> 6) & 63);
    const int c = (int)((idx >> 12) & 127);
    const long base = (idx >> 12) << 12;   // plane start
    const float* p = in + base;
    const float* kw = wts + c * 9;
    float acc = 0.f;
#pragma unroll
    for (int dh = -1; dh <= 1; dh++) {
        int hh = h + dh;
        if ((unsigned)hh >= 64u) continue;
#pragma unroll
        for (int dw = -1; dw <= 1; dw++) {
            int ww2 = w + dw;
            if ((unsigned)ww2 >= 64u) continue;
            acc += p[hh * 64 + ww2] * kw[(dh + 1) * 3 + (dw + 1)];
        }
    }
    acc += bias[c];
    out[idx] = siluf(acc);
}

// ---------------- per-plane 64x64 transpose (= or +=) ----------------
// dst[r*64+c] (=/+=) src[c*64+r] ; grid = B*C planes
template <bool ADD>
__global__ __launch_bounds__(256) void transp_k(const float* __restrict__ src,
                                                float* __restrict__ dst)
{
    __shared__ float t[64][65];
    const long plane = blockIdx.x;
    const float* s = src + plane * (long)L_;
    float* d = dst + plane * (long)L_;
    const int tid = threadIdx.x;
#pragma unroll
    for (int i = 0; i < 16; i++) {
        int idx = tid + i * 256;
        t[idx >> 6][idx & 63] = s[idx];
    }
    __syncthreads();
#pragma unroll
    for (int i = 0; i < 16; i++) {
        int idx = tid + i * 256;
        int r = idx >> 6, cc = idx & 63;
        float val = t[cc][r];
        if (ADD) d[idx] += val; else d[idx] = val;
    }
}

// ---------------- x_dbl projection: out[b,k,l,0:16] = x_proj_w[k] @ xs ----------------
// grid = (L/64, K, B); block 256 = 64 l's x 4 d-groups
__global__ __launch_bounds__(256) void xdbl_k(const float* __restrict__ u,
                                              const float* __restrict__ uT,
                                              const float* __restrict__ xw,
                                              float* __restrict__ out)
{
    __shared__ float wsm[16][132];
    const int k = blockIdx.y, b = blockIdx.z;
    const int tid = threadIdx.x;
#pragma unroll
    for (int i = 0; i < 8; i++) {
        int idx = tid * 8 + i;               // 0..2047
        wsm[idx >> 7][idx & 127] = xw[k * 2048 + idx];
    }
    __syncthreads();
    const int dg = (tid & 3) * 4;
    const int lo = tid >> 2;                 // 0..63
    const int l = blockIdx.x * 64 + lo;
    const int pos = (k >= 2) ? (L_ - 1 - l) : l;
    const float* usrc = ((k & 1) ? uT : u) + (long)b * C_ * L_ + pos;
    float a0 = 0.f, a1 = 0.f, a2 = 0.f, a3 = 0.f;
#pragma unroll 4
    for (int c = 0; c < C_; c++) {
        float uc = usrc[(long)c * L_];
        a0 += wsm[dg + 0][c] * uc;
        a1 += wsm[dg + 1][c] * uc;
        a2 += wsm[dg + 2][c] * uc;
        a3 += wsm[dg + 3][c] * uc;
    }
    float4 o = make_float4(a0, a1, a2, a3);
    *(float4*)(out + (((long)(b * K_ + k) * L_ + l) << 4) + dg) = o;
}

// ---------------- scan phase 1: per-chunk (P = prod dA, S = state from 0) ----------------
__global__ __launch_bounds__(256) void scan_ph1_k(const float* __restrict__ xdbl,
                                                  const float* __restrict__ u,
                                                  const float* __restrict__ uT,
                                                  const float* __restrict__ dtw,
                                                  const float* __restrict__ dtb,
                                                  const float* __restrict__ alogs,
                                                  float* __restrict__ st)
{
    const long t = (long)blockIdx.x * 256 + threadIdx.x;   // B*K*C*NCH = 262144
    const int chunk = (int)(t & 63);
    const long chain = t >> 6;                              // 4096
    const int c = (int)(chain & 127);
    const int bk = (int)(chain >> 7);
    const int k = bk & 3, b = bk >> 2;
    const float4* xd = (const float4*)(xdbl + (((long)(b * K_ + k) * L_) << 4));
    const float* usrc = ((k & 1) ? uT : u) + ((long)b * C_ + c) * L_;
    const bool rev = (k >= 2);
    float dw[8];
#pragma unroll
    for (int r = 0; r < 8; r++) dw[r] = dtw[((k * C_ + c) << 3) + r];
    const float db = dtb[k * C_ + c];
    float An[4];
#pragma unroll
    for (int n = 0; n < 4; n++) An[n] = -expf(alogs[((k * C_ + c) << 2) + n]);
    float P0 = 1.f, P1 = 1.f, P2 = 1.f, P3 = 1.f;
    float S0 = 0.f, S1 = 0.f, S2 = 0.f, S3 = 0.f;
    const int l0 = chunk * CH_;
    for (int i = 0; i < CH_; i++) {
        int l = l0 + i;
        int pos = rev ? (L_ - 1 - l) : l;
        float4 d0 = xd[l * 4 + 0];
        float4 d1 = xd[l * 4 + 1];
        float4 bs = xd[l * 4 + 2];
        float uv = usrc[pos];
        float z = db + d0.x * dw[0] + d0.y * dw[1] + d0.z * dw[2] + d0.w * dw[3]
                     + d1.x * dw[4] + d1.y * dw[5] + d1.z * dw[6] + d1.w * dw[7];
        float delta = softplusf(z);
        float du = delta * uv;
        float e;
        e = expf(delta * An[0]); S0 = e * S0 + du * bs.x; P0 *= e;
        e = expf(delta * An[1]); S1 = e * S1 + du * bs.y; P1 *= e;
        e = expf(delta * An[2]); S2 = e * S2 + du * bs.z; P2 *= e;
        e = expf(delta * An[3]); S3 = e * S3 + du * bs.w; P3 *= e;
    }
    float* o = st + (chain << 9) + (chunk << 3);
    *(float4*)o = make_float4(P0, P1, P2, P3);
    *(float4*)(o + 4) = make_float4(S0, S1, S2, S3);
}

// ---------------- scan mid: chain chunk boundaries, store entering state ----------------
__global__ __launch_bounds__(256) void scan_mid_k(float* __restrict__ st)
{
    const long chain = (long)blockIdx.x * 256 + threadIdx.x;   // 4096
    float* base = st + (chain << 9);
    float4 H = make_float4(0.f, 0.f, 0.f, 0.f);
    for (int j = 0; j < NCH_; j++) {
        float4 P = *(float4*)(base + (j << 3));
        float4 S = *(float4*)(base + (j << 3) + 4);
        *(float4*)(base + (j << 3) + 4) = H;          // entering state for chunk j
        H.x = S.x + P.x * H.x; H.y = S.y + P.y * H.y;
        H.z = S.z + P.z * H.z; H.w = S.w + P.w * H.w;
    }
}

// ---------------- scan phase 2: replay chunk with true init, emit y ----------------
// STORE pass: grid.y in {0,1} -> k = gy ('='); ADD pass: k = gy+2 ('+=')
template <bool STORE>
__global__ __launch_bounds__(256) void scan_ph2_k(const float* __restrict__ xdbl,
                                                  const float* __restrict__ u,
                                                  const float* __restrict__ uT,
                                                  const float* __restrict__ dtw,
                                                  const float* __restrict__ dtb,
                                                  const float* __restrict__ alogs,
                                                  const float* __restrict__ Dsp,
                                                  const float* __restrict__ st,
                                                  float* __restrict__ Y0,
                                                  float* __restrict__ Yt)
{
    const int k = STORE ? blockIdx.y : (blockIdx.y + 2);
    const long t = (long)blockIdx.x * 256 + threadIdx.x;   // B*C*NCH = 65536
    const int chunk = (int)(t & 63);
    const long bc = t >> 6;                                 // 1024
    const int c = (int)(bc & 127);
    const int b = (int)(bc >> 7);
    const long chain = (long)(b * K_ + k) * C_ + c;
    const float4* xd = (const float4*)(xdbl + (((long)(b * K_ + k) * L_) << 4));
    const float* usrc = ((k & 1) ? uT : u) + ((long)b * C_ + c) * L_;
    float* ydst = ((k & 1) ? Yt : Y0) + ((long)b * C_ + c) * L_;
    const bool rev = (k >= 2);
    float dw[8];
#pragma unroll
    for (int r = 0; r < 8; r++) dw[r] = dtw[((k * C_ + c) << 3) + r];
    const float db = dtb[k * C_ + c];
    float An[4];
#pragma unroll
    for (int n = 0; n < 4; n++) An[n] = -expf(alogs[((k * C_ + c) << 2) + n]);
    const float Dc = Dsp[k * C_ + c];
    float4 H = *(const float4*)(st + (chain << 9) + (chunk << 3) + 4);
    float h0 = H.x, h1 = H.y, h2 = H.z, h3 = H.w;
    const int l0 = chunk * CH_;
    for (int i = 0; i < CH_; i++) {
        int l = l0 + i;
        int pos = rev ? (L_ - 1 - l) : l;
        float4 d0 = xd[l * 4 + 0];
        float4 d1 = xd[l * 4 + 1];
        float4 bs = xd[l * 4 + 2];
        float4 cs = xd[l * 4 + 3];
        float uv = usrc[pos];
        float z = db + d0.x * dw[0] + d0.y * dw[1] + d0.z * dw[2] + d0.w * dw[3]
                     + d1.x * dw[4] + d1.y * dw[5] + d1.z * dw[6] + d1.w * dw[7];
        float delta = softplusf(z);
        float du = delta * uv;
        float e;
        e = expf(delta * An[0]); h0 = e * h0 + du * bs.x;
        e = expf(delta * An[1]); h1 = e * h1 + du * bs.y;
        e = expf(delta * An[2]); h2 = e * h2 + du * bs.z;
        e = expf(delta * An[3]); h3 = e * h3 + du * bs.w;
        float y = h0 * cs.x + h1 * cs.y + h2 * cs.z + h3 * cs.w + Dc * uv;
        if (STORE) ydst[pos] = y; else ydst[pos] += y;
    }
}

// ---------------- final blend: out = g*z + (1-g)*h ----------------
__global__ __launch_bounds__(256) void final_k(const float* __restrict__ g,
                                               const float* __restrict__ z,
                                               const float* __restrict__ h,
                                               float* __restrict__ out)
{
    const long i = ((long)blockIdx.x * 256 + threadIdx.x) * 4;
    float4 gv = *(const float4*)(g + i);
    float4 zv = *(const float4*)(z + i);
    float4 hv = *(const float4*)(h + i);
    float4 o;
    o.x = hv.x + gv.x * (zv.x - hv.x);
    o.y = hv.y + gv.y * (zv.y - hv.y);
    o.z = hv.z + gv.z * (zv.z - hv.z);
    o.w = hv.w + gv.w * (zv.w - hv.w);
    *(float4*)(out + i) = o;
}

// ---------------- launch ----------------
extern "C" void kernel_launch(void* const* d_in, const int* in_sizes, int n_in,
                              void* d_out, int out_size, void* d_ws, size_t ws_size,
                              hipStream_t stream)
{
    const float* h_in      = (const float*)d_in[0];
    const float* x_in      = (const float*)d_in[4];
    const float* in_proj_w = (const float*)d_in[5];
    const float* in_proj_b = (const float*)d_in[6];
    const float* ln1_g     = (const float*)d_in[7];
    const float* ln1_b     = (const float*)d_in[8];
    const float* ssm_in_w  = (const float*)d_in[9];
    const float* conv_w    = (const float*)d_in[10];
    const float* conv_b    = (const float*)d_in[11];
    const float* x_proj_w  = (const float*)d_in[12];
    const float* dt_w      = (const float*)d_in[13];
    const float* dt_b      = (const float*)d_in[14];
    const float* A_logs    = (const float*)d_in[15];
    const float* Dsp       = (const float*)d_in[16];
    const float* outnorm_g = (const float*)d_in[17];
    const float* outnorm_b = (const float*)d_in[18];
    const float* out_proj_w= (const float*)d_in[19];
    const float* ln2_g     = (const float*)d_in[20];
    const float* ln2_b     = (const float*)d_in[21];
    const float* fc1_w     = (const float*)d_in[22];
    const float* fc1_b     = (const float*)d_in[23];
    const float* fc2_w     = (const float*)d_in[24];
    const float* fc2_b     = (const float*)d_in[25];
    const float* gate_w    = (const float*)d_in[26];
    const float* gate_b    = (const float*)d_in[27];

    float* ws   = (float*)d_ws;
    float* fz   = ws;              // feat -> z (in place)
    float* ubuf = ws + SZ1;        // u ; MLP hidden m overlays [SZ1, 3*SZ1)
    float* tbuf = ws + 2 * SZ1;    // u0 -> u_T -> y_norm
    float* ybuf = ws + 3 * SZ1;    // ln1out -> Y0 -> ln2out
    float* xdbl = ws + 4 * SZ1;    // [B,K,L,16] = 2,097,152 floats
    float* stbf = ws + 4 * SZ1 + 2097152;  // scan states, 2,097,152 floats
    float* mbuf = ubuf;            // MLP hidden for 4 batches (2*SZ1 floats)
    float* gbuf = (float*)d_out;   // hosts Yt, then gate, then final output

    const dim3 blk(256);
    const long sBC = (long)C_ * L_;
    const long sX  = (long)CIN_ * L_;
    const long sM  = (long)DFF_ * L_;

    // 1) feat = in_proj @ concat(h, x) + b
    gemm_k<false, true, false, false, true><<<dim3(64, 1, 8), blk, 0, stream>>>(
        in_proj_w, h_in, sBC, x_in, sX, 128, in_proj_b, fz, sBC, 128, L_, 320);
    // 2) ln1(feat) -> ybuf
    ln_cf_k<<<dim3(512), blk, 0, stream>>>(fz, ln1_g, ln1_b, ybuf);
    // 3) u0 = ssm_in @ ln1 -> tbuf
    gemm_k<false, false, false, false, false><<<dim3(64, 1, 8), blk, 0, stream>>>(
        ssm_in_w, ybuf, sBC, nullptr, 0, 1 << 30, nullptr, tbuf, sBC, 128, L_, 128);
    // 4) u = silu(dwconv(u0) + conv_b) -> ubuf
    dwconv_silu_k<<<dim3(16384), blk, 0, stream>>>(tbuf, conv_w, conv_b, ubuf);
    // 5) u_T -> tbuf
    transp_k<false><<<dim3(1024), blk, 0, stream>>>(ubuf, tbuf);
    // 6) x_dbl
    xdbl_k<<<dim3(64, 4, 8), blk, 0, stream>>>(ubuf, tbuf, x_proj_w, xdbl);
    // 7) scan phase 1
    scan_ph1_k<<<dim3(1024), blk, 0, stream>>>(xdbl, ubuf, tbuf, dt_w, dt_b, A_logs, stbf);
    // 8) chunk-boundary chaining
    scan_mid_k<<<dim3(16), blk, 0, stream>>>(stbf);
    // 9) scan phase 2, k=0 -> Y0 '=', k=1 -> Yt '='
    scan_ph2_k<true><<<dim3(256, 2), blk, 0, stream>>>(xdbl, ubuf, tbuf, dt_w, dt_b,
                                                       A_logs, Dsp, stbf, ybuf, gbuf);
    // 10) scan phase 2, k=2 -> Y0 '+=', k=3 -> Yt '+='
    scan_ph2_k<false><<<dim3(256, 2), blk, 0, stream>>>(xdbl, ubuf, tbuf, dt_w, dt_b,
                                                        A_logs, Dsp, stbf, ybuf, gbuf);
    // 11) Y0 += transpose(Yt)
    transp_k<true><<<dim3(1024), blk, 0, stream>>>(gbuf, ybuf);
    // 12) outnorm(Y0) -> tbuf
    ln_cf_k<<<dim3(512), blk, 0, stream>>>(ybuf, outnorm_g, outnorm_b, tbuf);
    // 13) z = feat + out_proj @ y_norm   (ACC into fz)
    gemm_k<true, false, false, false, false><<<dim3(64, 1, 8), blk, 0, stream>>>(
        out_proj_w, tbuf, sBC, nullptr, 0, 1 << 30, nullptr, fz, sBC, 128, L_, 128);
    // 14) ln2(z) -> ybuf
    ln_cf_k<<<dim3(512), blk, 0, stream>>>(fz, ln2_g, ln2_b, ybuf);
    // 15-18) MLP in two 4-batch halves (hidden overlays dead u/u_T buffers)
    for (int half = 0; half < 2; half++) {
        long o = (long)half * 4 * sBC;
        gemm_k<false, true, false, false, false><<<dim3(64, 4, 4), blk, 0, stream>>>(
            fc1_w, ybuf + o, sBC, nullptr, 0, 1 << 30, fc1_b, mbuf, sM, 512, L_, 128);
        gemm_k<true, true, true, false, false><<<dim3(64, 1, 4), blk, 0, stream>>>(
            fc2_w, mbuf, sM, nullptr, 0, 1 << 30, fc2_b, fz + o, sBC, 128, L_, 512);
    }
    // 19) g = sigmoid(gate @ z + b) -> gbuf (d_out)
    gemm_k<false, true, false, true, false><<<dim3(64, 1, 8), blk, 0, stream>>>(
        gate_w, fz, sBC, nullptr, 0, 1 << 30, gate_b, gbuf, sBC, 128, L_, 128);
    // 20) out = g*z + (1-g)*h
    final_k<<<dim3(4096), blk, 0, stream>>>(gbuf, fz, h_in, (float*)d_out);
}

// Round 2
// 593.366 us; speedup vs baseline: 1.8202x; 1.8202x over previous
//
#include <hip/hip_runtime.h>
#include <hip/hip_bf16.h>

// ---------------- constants ----------------
constexpr int B_ = 8, C_ = 128, Hh = 64, Ww = 64, L_ = Hh * Ww;   // L = 4096
constexpr int CIN_ = 192, K_ = 4, Rr = 8, DFF_ = 512;
constexpr long SZ1 = (long)B_ * C_ * L_;                           // 4,194,304 floats
constexpr int CH_ = 64, NCH_ = L_ / CH_;                           // 64 chunks of 64
constexpr float EPSf = 1e-5f;

#define DEVI __device__ __forceinline__

DEVI float sigm(float x) { return 1.f / (1.f + expf(-x)); }
DEVI float softplusf(float x) { return x > 20.f ? x : log1pf(expf(x)); }
DEVI float geluf(float x) { return 0.5f * x * (1.f + erff(x * 0.70710678118654752f)); }
DEVI float siluf(float x) { return x * sigm(x); }

// transposed-plane ("scan order") address of position pos in a 64x64 plane
DEVI int tadr(int pos) { return ((pos & 63) << 6) | (pos >> 6); }

// ---------------- generic tiled fp32 GEMM ----------------
template <bool ACC, bool BIAS, bool XGELU, bool SIG, bool SPLIT>
__global__ __launch_bounds__(256) void gemm_k(
    const float* __restrict__ W, const float* __restrict__ X1, long sX1,
    const float* __restrict__ X2, long sX2, int splitRow,
    const float* __restrict__ bias, float* __restrict__ Cp, long sC,
    int M, int N, int K)
{
    __shared__ float sW[32][128];
    __shared__ float sX[32][64];
    const int tid = threadIdx.x;
    const int bn = blockIdx.x, bm = blockIdx.y, bz = blockIdx.z;
    const float* X1b = X1 + (long)bz * sX1;
    const float* X2b = SPLIT ? (X2 + (long)bz * sX2) : nullptr;
    float* Cb = Cp + (long)bz * sC;
    const int n0 = bn * 64, m0 = bm * 128;
    const int tx = tid & 15, ty = tid >> 4;

    float acc[8][4];
#pragma unroll
    for (int i = 0; i < 8; i++)
#pragma unroll
        for (int j = 0; j < 4; j++) acc[i][j] = 0.f;

    const int wrow = tid >> 1;
    const int wk0  = (tid & 1) * 16;
    const int xrow = tid >> 3;
    const int xcol = (tid & 7) * 8;

    for (int k0 = 0; k0 < K; k0 += 32) {
        {
            const float* wp = W + (long)(m0 + wrow) * K + k0 + wk0;
#pragma unroll
            for (int j = 0; j < 4; j++) {
                float4 v = *(const float4*)(wp + j * 4);
                int kk = wk0 + j * 4;
                sW[kk + 0][wrow] = v.x; sW[kk + 1][wrow] = v.y;
                sW[kk + 2][wrow] = v.z; sW[kk + 3][wrow] = v.w;
            }
        }
        {
            const int krow = k0 + xrow;
            const float* xp;
            if (SPLIT && krow >= splitRow)
                xp = X2b + (long)(krow - splitRow) * N + n0 + xcol;
            else
                xp = X1b + (long)krow * N + n0 + xcol;
            float4 a = *(const float4*)xp;
            float4 b = *(const float4*)(xp + 4);
            if (XGELU) {
                a.x = geluf(a.x); a.y = geluf(a.y); a.z = geluf(a.z); a.w = geluf(a.w);
                b.x = geluf(b.x); b.y = geluf(b.y); b.z = geluf(b.z); b.w = geluf(b.w);
            }
            *(float4*)&sX[xrow][xcol] = a;
            *(float4*)&sX[xrow][xcol + 4] = b;
        }
        __syncthreads();
#pragma unroll
        for (int kk = 0; kk < 32; kk++) {
            float4 xv = *(const float4*)&sX[kk][tx << 2];
            float4 wa = *(const float4*)&sW[kk][ty << 3];
            float4 wb = *(const float4*)&sW[kk][(ty << 3) + 4];
            float wv[8] = {wa.x, wa.y, wa.z, wa.w, wb.x, wb.y, wb.z, wb.w};
            float xu[4] = {xv.x, xv.y, xv.z, xv.w};
#pragma unroll
            for (int i = 0; i < 8; i++)
#pragma unroll
                for (int j = 0; j < 4; j++) acc[i][j] += wv[i] * xu[j];
        }
        __syncthreads();
    }

#pragma unroll
    for (int i = 0; i < 8; i++) {
        int m = m0 + (ty << 3) + i;
        float bv = BIAS ? bias[m] : 0.f;
        float* cp = Cb + (long)m * N + n0 + (tx << 2);
        float4 o = make_float4(acc[i][0] + bv, acc[i][1] + bv, acc[i][2] + bv, acc[i][3] + bv);
        if (ACC) {
            float4 p = *(const float4*)cp;
            o.x += p.x; o.y += p.y; o.z += p.z; o.w += p.w;
        }
        if (SIG) { o.x = sigm(o.x); o.y = sigm(o.y); o.z = sigm(o.z); o.w = sigm(o.w); }
        *(float4*)cp = o;
    }
}

// ---------------- channel LayerNorm (channel_first) ----------------
__global__ __launch_bounds__(256) void ln_cf_k(const float* __restrict__ in,
                                               const float* __restrict__ g,
                                               const float* __restrict__ bta,
                                               float* __restrict__ out)
{
    __shared__ float s1[4][64], s2[4][64];
    const int tid = threadIdx.x;
    const int p = tid & 63, q = tid >> 6;
    const long posg = (long)blockIdx.x * 64 + p;
    const int b = (int)(posg / L_);
    const int pp = (int)(posg % L_);
    const float* base = in + ((long)b * C_ + q * 32) * L_ + pp;
    float v[32];
    float s = 0.f, sq = 0.f;
#pragma unroll
    for (int i = 0; i < 32; i++) {
        float t = base[(long)i * L_];
        v[i] = t; s += t; sq += t * t;
    }
    s1[q][p] = s; s2[q][p] = sq;
    __syncthreads();
    float ts = s1[0][p] + s1[1][p] + s1[2][p] + s1[3][p];
    float tq = s2[0][p] + s2[1][p] + s2[2][p] + s2[3][p];
    float mu = ts * (1.f / 128.f);
    float var = tq * (1.f / 128.f) - mu * mu;
    float rs = rsqrtf(var + EPSf);
    float* ob = out + ((long)b * C_ + q * 32) * L_ + pp;
#pragma unroll
    for (int i = 0; i < 32; i++) {
        int c = q * 32 + i;
        ob[(long)i * L_] = (v[i] - mu) * rs * g[c] + bta[c];
    }
}

// ---------------- depthwise 3x3 conv + bias + SiLU ----------------
__global__ __launch_bounds__(256) void dwconv_silu_k(const float* __restrict__ in,
                                                     const float* __restrict__ wts,
                                                     const float* __restrict__ bias,
                                                     float* __restrict__ out)
{
    const long idx = (long)blockIdx.x * 256 + threadIdx.x;
    const int w = (int)(idx & 63);
    const int h = (int)((idx >> 6) & 63);
    const int c = (int)((idx >> 12) & 127);
    const long base = (idx >> 12) << 12;
    const float* p = in + base;
    const float* kw = wts + c * 9;
    float acc = 0.f;
#pragma unroll
    for (int dh = -1; dh <= 1; dh++) {
        int hh = h + dh;
        if ((unsigned)hh >= 64u) continue;
#pragma unroll
        for (int dw = -1; dw <= 1; dw++) {
            int ww2 = w + dw;
            if ((unsigned)ww2 >= 64u) continue;
            acc += p[hh * 64 + ww2] * kw[(dh + 1) * 3 + (dw + 1)];
        }
    }
    acc += bias[c];
    out[idx] = siluf(acc);
}

// ---------------- per-plane 64x64 transpose (= or +=) ----------------
template <bool ADD>
__global__ __launch_bounds__(256) void transp_k(const float* __restrict__ src,
                                                float* __restrict__ dst)
{
    __shared__ float t[64][65];
    const long plane = blockIdx.x;
    const float* s = src + plane * (long)L_;
    float* d = dst + plane * (long)L_;
    const int tid = threadIdx.x;
#pragma unroll
    for (int i = 0; i < 16; i++) {
        int idx = tid + i * 256;
        t[idx >> 6][idx & 63] = s[idx];
    }
    __syncthreads();
#pragma unroll
    for (int i = 0; i < 16; i++) {
        int idx = tid + i * 256;
        int r = idx >> 6, cc = idx & 63;
        float val = t[cc][r];
        if (ADD) d[idx] += val; else d[idx] = val;
    }
}

// ---------------- x_dbl projection (stored in SCAN ORDER: s(l) = transposed addr) ----------------
__global__ __launch_bounds__(256) void xdbl_k(const float* __restrict__ u,
                                              const float* __restrict__ uT,
                                              const float* __restrict__ xw,
                                              float* __restrict__ out)
{
    __shared__ float wsm[16][132];
    const int k = blockIdx.y, b = blockIdx.z;
    const int tid = threadIdx.x;
#pragma unroll
    for (int i = 0; i < 8; i++) {
        int idx = tid * 8 + i;
        wsm[idx >> 7][idx & 127] = xw[k * 2048 + idx];
    }
    __syncthreads();
    const int dg = (tid & 3) * 4;
    const int lo = tid >> 2;
    const int l = blockIdx.x * 64 + lo;
    const int pos = (k >= 2) ? (L_ - 1 - l) : l;
    const float* usrc = ((k & 1) ? uT : u) + (long)b * C_ * L_ + pos;
    float a0 = 0.f, a1 = 0.f, a2 = 0.f, a3 = 0.f;
#pragma unroll 4
    for (int c = 0; c < C_; c++) {
        float uc = usrc[(long)c * L_];
        a0 += wsm[dg + 0][c] * uc;
        a1 += wsm[dg + 1][c] * uc;
        a2 += wsm[dg + 2][c] * uc;
        a3 += wsm[dg + 3][c] * uc;
    }
    float4 o = make_float4(a0, a1, a2, a3);
    const long s = tadr(l);
    *(float4*)(out + (((long)(b * K_ + k) * L_ + s) << 4) + dg) = o;
}

// ---------------- scan phase 1 ----------------
__global__ __launch_bounds__(256) void scan_ph1_k(const float* __restrict__ xdbl,
                                                  const float* __restrict__ u,
                                                  const float* __restrict__ uT,
                                                  const float* __restrict__ dtw,
                                                  const float* __restrict__ dtb,
                                                  const float* __restrict__ alogs,
                                                  float* __restrict__ st)
{
    const long t = (long)blockIdx.x * 256 + threadIdx.x;   // B*K*C*NCH
    const int j = (int)(t & 63);                            // chunk = lane
    const long chain = t >> 6;
    const int c = (int)(chain & 127);
    const int bk = (int)(chain >> 7);
    const int k = bk & 3, b = bk >> 2;
    const float4* xd = (const float4*)(xdbl + (((long)(b * K_ + k) * L_) << 4));
    // read TRANSPOSE of the scan-domain plane -> coalesced
    const float* usrc = ((k & 1) ? u : uT) + ((long)b * C_ + c) * L_;
    const bool rev = (k >= 2);
    float dw[8];
#pragma unroll
    for (int r = 0; r < 8; r++) dw[r] = dtw[((k * C_ + c) << 3) + r];
    const float db = dtb[k * C_ + c];
    float An[4];
#pragma unroll
    for (int n = 0; n < 4; n++) An[n] = -expf(alogs[((k * C_ + c) << 2) + n]);
    float P0 = 1.f, P1 = 1.f, P2 = 1.f, P3 = 1.f;
    float S0 = 0.f, S1 = 0.f, S2 = 0.f, S3 = 0.f;
    for (int i = 0; i < CH_; i++) {
        int sidx = (i << 6) | j;                    // scan-order index
        int l = (j << 6) | i;
        int pos = rev ? (L_ - 1 - l) : l;
        float4 d0 = xd[sidx * 4 + 0];
        float4 d1 = xd[sidx * 4 + 1];
        float4 bs = xd[sidx * 4 + 2];
        float uv = usrc[tadr(pos)];
        float z = db + d0.x * dw[0] + d0.y * dw[1] + d0.z * dw[2] + d0.w * dw[3]
                     + d1.x * dw[4] + d1.y * dw[5] + d1.z * dw[6] + d1.w * dw[7];
        float delta = softplusf(z);
        float du = delta * uv;
        float e;
        e = expf(delta * An[0]); S0 = e * S0 + du * bs.x; P0 *= e;
        e = expf(delta * An[1]); S1 = e * S1 + du * bs.y; P1 *= e;
        e = expf(delta * An[2]); S2 = e * S2 + du * bs.z; P2 *= e;
        e = expf(delta * An[3]); S3 = e * S3 + du * bs.w; P3 *= e;
    }
    float* o = st + (chain << 9) + (j << 3);
    *(float4*)o = make_float4(P0, P1, P2, P3);
    *(float4*)(o + 4) = make_float4(S0, S1, S2, S3);
}

// ---------------- scan mid: wave-parallel scan over 64 chunk-(P,S) pairs ----------------
__global__ __launch_bounds__(256) void scan_mid_k(float* __restrict__ st)
{
    const long chain = ((long)blockIdx.x * 256 + threadIdx.x) >> 6;
    const int lane = threadIdx.x & 63;
    float* base = st + (chain << 9) + (lane << 3);
    float4 P = *(float4*)base;
    float4 S = *(float4*)(base + 4);
#pragma unroll
    for (int d = 1; d < 64; d <<= 1) {
        float4 Pu, Su;
        Pu.x = __shfl_up(P.x, d, 64); Pu.y = __shfl_up(P.y, d, 64);
        Pu.z = __shfl_up(P.z, d, 64); Pu.w = __shfl_up(P.w, d, 64);
        Su.x = __shfl_up(S.x, d, 64); Su.y = __shfl_up(S.y, d, 64);
        Su.z = __shfl_up(S.z, d, 64); Su.w = __shfl_up(S.w, d, 64);
        if (lane >= d) {
            S.x += P.x * Su.x; S.y += P.y * Su.y;
            S.z += P.z * Su.z; S.w += P.w * Su.w;
            P.x *= Pu.x; P.y *= Pu.y; P.z *= Pu.z; P.w *= Pu.w;
        }
    }
    // entering state for chunk j = inclusive result of chunk j-1 (0 for j=0)
    float4 E;
    E.x = __shfl_up(S.x, 1, 64); E.y = __shfl_up(S.y, 1, 64);
    E.z = __shfl_up(S.z, 1, 64); E.w = __shfl_up(S.w, 1, 64);
    if (lane == 0) { E.x = 0.f; E.y = 0.f; E.z = 0.f; E.w = 0.f; }
    *(float4*)(base + 4) = E;
}

// ---------------- scan phase 2 ----------------
template <bool STORE>
__global__ __launch_bounds__(256) void scan_ph2_k(const float* __restrict__ xdbl,
                                                  const float* __restrict__ u,
                                                  const float* __restrict__ uT,
                                                  const float* __restrict__ dtw,
                                                  const float* __restrict__ dtb,
                                                  const float* __restrict__ alogs,
                                                  const float* __restrict__ Dsp,
                                                  const float* __restrict__ st,
                                                  float* __restrict__ Y0,
                                                  float* __restrict__ Yt)
{
    const int k = STORE ? blockIdx.y : (blockIdx.y + 2);
    const long t = (long)blockIdx.x * 256 + threadIdx.x;   // B*C*NCH
    const int j = (int)(t & 63);
    const long bc = t >> 6;
    const int c = (int)(bc & 127);
    const int b = (int)(bc >> 7);
    const long chain = (long)(b * K_ + k) * C_ + c;
    const float4* xd = (const float4*)(xdbl + (((long)(b * K_ + k) * L_) << 4));
    const float* usrc = ((k & 1) ? u : uT) + ((long)b * C_ + c) * L_;
    float* ydst = ((k & 1) ? Yt : Y0) + ((long)b * C_ + c) * L_;
    const bool rev = (k >= 2);
    float dw[8];
#pragma unroll
    for (int r = 0; r < 8; r++) dw[r] = dtw[((k * C_ + c) << 3) + r];
    const float db = dtb[k * C_ + c];
    float An[4];
#pragma unroll
    for (int n = 0; n < 4; n++) An[n] = -expf(alogs[((k * C_ + c) << 2) + n]);
    const float Dc = Dsp[k * C_ + c];
    float4 H = *(const float4*)(st + (chain << 9) + (j << 3) + 4);
    float h0 = H.x, h1 = H.y, h2 = H.z, h3 = H.w;
    for (int i = 0; i < CH_; i++) {
        int sidx = (i << 6) | j;
        int l = (j << 6) | i;
        int pos = rev ? (L_ - 1 - l) : l;
        int ta = tadr(pos);
        float4 d0 = xd[sidx * 4 + 0];
        float4 d1 = xd[sidx * 4 + 1];
        float4 bs = xd[sidx * 4 + 2];
        float4 cs = xd[sidx * 4 + 3];
        float uv = usrc[ta];
        float z = db + d0.x * dw[0] + d0.y * dw[1] + d0.z * dw[2] + d0.w * dw[3]
                     + d1.x * dw[4] + d1.y * dw[5] + d1.z * dw[6] + d1.w * dw[7];
        float delta = softplusf(z);
        float du = delta * uv;
        float e;
        e = expf(delta * An[0]); h0 = e * h0 + du * bs.x;
        e = expf(delta * An[1]); h1 = e * h1 + du * bs.y;
        e = expf(delta * An[2]); h2 = e * h2 + du * bs.z;
        e = expf(delta * An[3]); h3 = e * h3 + du * bs.w;
        float y = h0 * cs.x + h1 * cs.y + h2 * cs.z + h3 * cs.w + Dc * uv;
        if (STORE) ydst[ta] = y; else ydst[ta] += y;
    }
}

// ---------------- final blend: out = g*z + (1-g)*h ----------------
__global__ __launch_bounds__(256) void final_k(const float* __restrict__ g,
                                               const float* __restrict__ z,
                                               const float* __restrict__ h,
                                               float* __restrict__ out)
{
    const long i = ((long)blockIdx.x * 256 + threadIdx.x) * 4;
    float4 gv = *(const float4*)(g + i);
    float4 zv = *(const float4*)(z + i);
    float4 hv = *(const float4*)(h + i);
    float4 o;
    o.x = hv.x + gv.x * (zv.x - hv.x);
    o.y = hv.y + gv.y * (zv.y - hv.y);
    o.z = hv.z + gv.z * (zv.z - hv.z);
    o.w = hv.w + gv.w * (zv.w - hv.w);
    *(float4*)(out + i) = o;
}

// ---------------- launch ----------------
extern "C" void kernel_launch(void* const* d_in, const int* in_sizes, int n_in,
                              void* d_out, int out_size, void* d_ws, size_t ws_size,
                              hipStream_t stream)
{
    const float* h_in      = (const float*)d_in[0];
    const float* x_in      = (const float*)d_in[4];
    const float* in_proj_w = (const float*)d_in[5];
    const float* in_proj_b = (const float*)d_in[6];
    const float* ln1_g     = (const float*)d_in[7];
    const float* ln1_b     = (const float*)d_in[8];
    const float* ssm_in_w  = (const float*)d_in[9];
    const float* conv_w    = (const float*)d_in[10];
    const float* conv_b    = (const float*)d_in[11];
    const float* x_proj_w  = (const float*)d_in[12];
    const float* dt_w      = (const float*)d_in[13];
    const float* dt_b      = (const float*)d_in[14];
    const float* A_logs    = (const float*)d_in[15];
    const float* Dsp       = (const float*)d_in[16];
    const float* outnorm_g = (const float*)d_in[17];
    const float* outnorm_b = (const float*)d_in[18];
    const float* out_proj_w= (const float*)d_in[19];
    const float* ln2_g     = (const float*)d_in[20];
    const float* ln2_b     = (const float*)d_in[21];
    const float* fc1_w     = (const float*)d_in[22];
    const float* fc1_b     = (const float*)d_in[23];
    const float* fc2_w     = (const float*)d_in[24];
    const float* fc2_b     = (const float*)d_in[25];
    const float* gate_w    = (const float*)d_in[26];
    const float* gate_b    = (const float*)d_in[27];

    float* ws   = (float*)d_ws;
    float* fz   = ws;              // feat -> z (in place)
    float* ubuf = ws + SZ1;        // u ; MLP hidden overlays
    float* tbuf = ws + 2 * SZ1;    // u0 -> u_T -> y_norm
    float* ybuf = ws + 3 * SZ1;    // ln1out -> TY0 -> ln2out
    float* xdbl = ws + 4 * SZ1;    // [B,K,L(scan order),16]
    float* stbf = ws + 4 * SZ1 + 2097152;
    float* mbuf = ubuf;
    float* gbuf = (float*)d_out;   // TYt -> merged y -> gate -> final out

    const dim3 blk(256);
    const long sBC = (long)C_ * L_;
    const long sX  = (long)CIN_ * L_;
    const long sM  = (long)DFF_ * L_;

    // 1) feat = in_proj @ concat(h, x) + b
    gemm_k<false, true, false, false, true><<<dim3(64, 1, 8), blk, 0, stream>>>(
        in_proj_w, h_in, sBC, x_in, sX, 128, in_proj_b, fz, sBC, 128, L_, 320);
    // 2) ln1(feat) -> ybuf
    ln_cf_k<<<dim3(512), blk, 0, stream>>>(fz, ln1_g, ln1_b, ybuf);
    // 3) u0 = ssm_in @ ln1 -> tbuf
    gemm_k<false, false, false, false, false><<<dim3(64, 1, 8), blk, 0, stream>>>(
        ssm_in_w, ybuf, sBC, nullptr, 0, 1 << 30, nullptr, tbuf, sBC, 128, L_, 128);
    // 4) u = silu(dwconv(u0) + conv_b) -> ubuf
    dwconv_silu_k<<<dim3(16384), blk, 0, stream>>>(tbuf, conv_w, conv_b, ubuf);
    // 5) u_T -> tbuf
    transp_k<false><<<dim3(1024), blk, 0, stream>>>(ubuf, tbuf);
    // 6) x_dbl (scan-order layout)
    xdbl_k<<<dim3(64, 4, 8), blk, 0, stream>>>(ubuf, tbuf, x_proj_w, xdbl);
    // 7) scan phase 1 (coalesced)
    scan_ph1_k<<<dim3(1024), blk, 0, stream>>>(xdbl, ubuf, tbuf, dt_w, dt_b, A_logs, stbf);
    // 8) chunk-boundary chaining (wave-parallel)
    scan_mid_k<<<dim3(1024), blk, 0, stream>>>(stbf);
    // 9) scan phase 2, k=0 -> TY0 '=', k=1 -> TYt '='
    scan_ph2_k<true><<<dim3(256, 2), blk, 0, stream>>>(xdbl, ubuf, tbuf, dt_w, dt_b,
                                                       A_logs, Dsp, stbf, ybuf, gbuf);
    // 10) scan phase 2, k=2 -> TY0 '+=', k=3 -> TYt '+='
    scan_ph2_k<false><<<dim3(256, 2), blk, 0, stream>>>(xdbl, ubuf, tbuf, dt_w, dt_b,
                                                        A_logs, Dsp, stbf, ybuf, gbuf);
    // 11) merged y = TYt + transpose(TY0)  (into gbuf)
    transp_k<true><<<dim3(1024), blk, 0, stream>>>(ybuf, gbuf);
    // 12) outnorm(y) -> tbuf
    ln_cf_k<<<dim3(512), blk, 0, stream>>>(gbuf, outnorm_g, outnorm_b, tbuf);
    // 13) z = feat + out_proj @ y_norm   (ACC into fz)
    gemm_k<true, false, false, false, false><<<dim3(64, 1, 8), blk, 0, stream>>>(
        out_proj_w, tbuf, sBC, nullptr, 0, 1 << 30, nullptr, fz, sBC, 128, L_, 128);
    // 14) ln2(z) -> ybuf
    ln_cf_k<<<dim3(512), blk, 0, stream>>>(fz, ln2_g, ln2_b, ybuf);
    // 15-18) MLP in two 4-batch halves
    for (int half = 0; half < 2; half++) {
        long o = (long)half * 4 * sBC;
        gemm_k<false, true, false, false, false><<<dim3(64, 4, 4), blk, 0, stream>>>(
            fc1_w, ybuf + o, sBC, nullptr, 0, 1 << 30, fc1_b, mbuf, sM, 512, L_, 128);
        gemm_k<true, true, true, false, false><<<dim3(64, 1, 4), blk, 0, stream>>>(
            fc2_w, mbuf, sM, nullptr, 0, 1 << 30, fc2_b, fz + o, sBC, 128, L_, 512);
    }
    // 19) g = sigmoid(gate @ z + b) -> gbuf
    gemm_k<false, true, false, true, false><<<dim3(64, 1, 8), blk, 0, stream>>>(
        gate_w, fz, sBC, nullptr, 0, 1 << 30, gate_b, gbuf, sBC, 128, L_, 128);
    // 20) out = g*z + (1-g)*h
    final_k<<<dim3(4096), blk, 0, stream>>>(gbuf, fz, h_in, (float*)d_out);
}